// Round 13
// baseline (175.052 us; speedup 1.0000x reference)
//
#include <hip/hip_runtime.h>

#define BB 2
#define HH 16
#define SS 2048
#define DD 64

constexpr int OSIZE = BB * HH * SS * DD;  // 4,194,304
constexpr float LOG2E = 1.4426950408889634f;

using bf16x8 = __attribute__((ext_vector_type(8))) short;
using bf16x4 = __attribute__((ext_vector_type(4))) short;
using f32x4  = __attribute__((ext_vector_type(4))) float;
using u16x8  = __attribute__((ext_vector_type(8))) unsigned short;
using fl4    = __attribute__((ext_vector_type(4))) float;

// gfx950 K=16 bf16 MFMA (v_mfma_f32_16x16x16_bf16)
#define MFMA16(a, b, c) __builtin_amdgcn_mfma_f32_16x16x16bf16_1k(a, b, c, 0, 0, 0)

__device__ __forceinline__ unsigned short f2bf(float f) {
    unsigned int u = __float_as_uint(f);
    return (unsigned short)((u + 0x7fffu + ((u >> 16) & 1u)) >> 16);
}

// pack two fp32 -> (bf16_hi<<16)|bf16_lo via one v_perm_b32 (truncation)
__device__ __forceinline__ unsigned int pkbf(float lo, float hi) {
    return __builtin_amdgcn_perm(__float_as_uint(hi), __float_as_uint(lo), 0x07060302u);
}

__device__ __forceinline__ void atomicMaxPosF(float* addr, float v) {
    atomicMax(reinterpret_cast<unsigned int*>(addr), __float_as_uint(v));
}

// ---- fused prepass: amax init + K->bf16 convert + V->bf16 transpose ----
__global__ __launch_bounds__(256) void prep_kv_kernel(
    const float* __restrict__ k, const float* __restrict__ v,
    const float* __restrict__ dsk, const float* __restrict__ dsv,
    unsigned short* __restrict__ kbf, unsigned short* __restrict__ vtb,
    float* __restrict__ out)
{
    const int t  = threadIdx.x;
    const int s0 = blockIdx.x * 64;
    const int bh = blockIdx.y;
    if (blockIdx.x == 0 && bh == 0 && t < 2) out[OSIZE + t] = 0.0f;

    const size_t base = (size_t)bh * SS * DD;
    const float sck = dsk[0], scv = dsv[0];

    {
        const float* kp = k + base + (size_t)s0 * DD + t * 16;
        unsigned short* ko = kbf + base + (size_t)s0 * DD + t * 16;
        fl4 a0 = ((const fl4*)kp)[0], a1 = ((const fl4*)kp)[1];
        fl4 a2 = ((const fl4*)kp)[2], a3 = ((const fl4*)kp)[3];
        u16x8 o0, o1;
        #pragma unroll
        for (int j = 0; j < 4; ++j) {
            o0[j] = f2bf(a0[j] * sck); o0[j + 4] = f2bf(a1[j] * sck);
            o1[j] = f2bf(a2[j] * sck); o1[j + 4] = f2bf(a3[j] * sck);
        }
        ((u16x8*)ko)[0] = o0; ((u16x8*)ko)[1] = o1;
    }

    __shared__ unsigned short T[64 * 72];
    {
        const int r  = t >> 2;
        const int cb = (t & 3) * 16;
        const fl4* vp = (const fl4*)(v + base + (size_t)(s0 + r) * DD + cb);
        unsigned short tmp[16];
        #pragma unroll
        for (int c = 0; c < 4; ++c) {
            fl4 xx = vp[c];
            #pragma unroll
            for (int j = 0; j < 4; ++j) tmp[c * 4 + j] = f2bf(xx[j] * scv);
        }
        *(u16x8*)&T[r * 72 + cb]     = *(u16x8*)&tmp[0];
        *(u16x8*)&T[r * 72 + cb + 8] = *(u16x8*)&tmp[8];
    }
    __syncthreads();
    {
        const int dr = t >> 2;
        const int sb = (t & 3) * 16;
        unsigned short tmp[16];
        #pragma unroll
        for (int j = 0; j < 16; ++j) tmp[j] = T[(sb + j) * 72 + dr];
        unsigned short* op = vtb + base + (size_t)dr * SS + s0 + sb;
        *(u16x8*)op       = *(u16x8*)&tmp[0];
        *(u16x8*)(op + 8) = *(u16x8*)&tmp[8];
    }
}

// ---- main kernel: 256-thr blocks (4/CU), 4 k-slice waves, 32 q-rows/block ----
__global__ __launch_bounds__(256, 4) void fattn_kernel(
    const float* __restrict__ q,
    const unsigned short* __restrict__ kbf,     // bf16 K  [bh][s][d], dsk folded
    const unsigned short* __restrict__ vtb,     // bf16 V^T [bh][d][s], dsv folded
    const float* __restrict__ dsq, const float* __restrict__ qss,
    const float* __restrict__ qso, const float* __restrict__ dss,
    float* __restrict__ out)
{
    const int bh = blockIdx.x;                  // flat%8 == bh%8 -> XCD-local K/V
    const int x  = blockIdx.y >> 1;             // 0..15 (qt pair {x, 31-x})
    const int qh = blockIdx.y & 1;              // q-half of the 64-row q-tile
    const int tid  = threadIdx.x;
    const int ks   = tid >> 6;                  // wave = k-slice 0..3 (16 k-rows each)
    const int lane = tid & 63;
    const int m16  = lane & 15;
    const int quad = lane >> 4;
    const int m7   = m16 & 7;

    // LDS: K dbuf 16KB + V dbuf 16KB + reductions ~0.5KB -> 4 blocks/CU
    __shared__ __align__(16) unsigned short Ksh[2][64 * 64];
    __shared__ __align__(16) unsigned short Vsh[2][64 * 64];
    __shared__ float Lred[4][2][16];   // [ks][nt][m16]
    __shared__ float Ered[4][2][16];

    const float q_scale = dsq[0] * 0.125f * LOG2E;
    const size_t base = (size_t)bh * SS * DD;
    const unsigned short* kbh = kbf + base;
    const unsigned short* vbh = vtb + base;

    // staging: 2 K + 2 V granules per thread; tid-LINEAR LDS writes, swizzled source
    // tile = 64 rows x 8 granules; granule g of row r holds src col g^(r&7)
    const int srow = tid >> 3;                  // 0..31 (second granule: +32 rows)
    const int sg   = tid & 7;
    const int ksrc0 = srow * DD + (sg ^ (srow & 7)) * 8;
    const int ksrc1 = ksrc0 + 32 * DD;          // (row+32)&7 == row&7
    const int vsrc0 = srow * SS + (sg ^ (srow & 7)) * 8;
    const int vsrc1 = vsrc0 + 32 * SS;
    const int lds0 = tid * 8, lds1 = (tid + 256) * 8;

    // fragment read offsets
    const int gsw0 = (quad ^ m7) * 8;           // K frag d-granules (swizzled)
    const int gsw1 = ((4 | quad) ^ m7) * 8;
    const int krow = (ks * 16 + m16) * 64;
    const int vg   = ks * 2 + (quad >> 1);
    const int vsw  = ((vg ^ m7) * 8) + (quad & 1) * 4;

    const float ss_ = qss[0] * dss[0];
    const float o_q = qso[0];
    float amax_o = 0.0f, amax_s = 0.0f;

    float* Ored = (float*)&Ksh[0][0];   // 16 KB overlay: 2 slots x 8 KB (2048 floats)

    for (int pass = 0; pass < 2; ++pass) {
        const int qt = pass ? (31 - x) : x;
        const int qb = qt * 64;
        const int nkt = qt + 1;

        // Q fragments (B operand) for this wave's 2 q-tiles, prescaled
        bf16x8 qf[2][2];
        #pragma unroll
        for (int nt = 0; nt < 2; ++nt) {
            const float* qp = q + base + (size_t)(qb + qh * 32 + nt * 16 + m16) * DD + quad * 8;
            #pragma unroll
            for (int f = 0; f < 2; ++f) {
                fl4 a = *(const fl4*)(qp + f * 32);
                fl4 b2 = *(const fl4*)(qp + f * 32 + 4);
                #pragma unroll
                for (int j = 0; j < 4; ++j) {
                    qf[nt][f][j]     = (short)f2bf(a[j] * q_scale);
                    qf[nt][f][j + 4] = (short)f2bf(b2[j] * q_scale);
                }
            }
        }

        f32x4 Oacc[4][2];   // O^T partial: row d=dt*16+quad*4+r, col q=nt*16+m16 (+qh*32)
        #pragma unroll
        for (int dt = 0; dt < 4; ++dt)
            #pragma unroll
            for (int nt = 0; nt < 2; ++nt)
                #pragma unroll
                for (int r = 0; r < 4; ++r) Oacc[dt][nt][r] = 0.0f;
        float l_l[2] = {0.0f, 0.0f}, e_m[2] = {0.0f, 0.0f};

        // stage tile 0 into buffer 0 (tid-linear writes)
        {
            *(u16x8*)&Ksh[0][lds0] = *(const u16x8*)(kbh + ksrc0);
            *(u16x8*)&Ksh[0][lds1] = *(const u16x8*)(kbh + ksrc1);
            *(u16x8*)&Vsh[0][lds0] = *(const u16x8*)(vbh + vsrc0);
            *(u16x8*)&Vsh[0][lds1] = *(const u16x8*)(vbh + vsrc1);
        }
        __syncthreads();

        for (int t = 0; t < nkt; ++t) {
            const int b = t & 1;
            const bool pf = (t + 1 < nkt);

            u16x8 kpf0, kpf1, vpf0, vpf1;
            if (pf) {
                const unsigned short* kg = kbh + (size_t)(t + 1) * 64 * DD;
                const unsigned short* vg2 = vbh + (t + 1) * 64;
                kpf0 = *(const u16x8*)(kg + ksrc0);
                kpf1 = *(const u16x8*)(kg + ksrc1);
                vpf0 = *(const u16x8*)(vg2 + vsrc0);
                vpf1 = *(const u16x8*)(vg2 + vsrc1);
            }

            const unsigned short* Kt = &Ksh[b][0];
            const unsigned short* Vt = &Vsh[b][0];

            // S^T slice = K(ks rows) Q^T : C[row=k=quad*4+r][col=q=m16], per q-tile nt
            bf16x8 kf0 = *(const bf16x8*)&Kt[krow + gsw0];
            bf16x8 kf1 = *(const bf16x8*)&Kt[krow + gsw1];
            f32x4 sacc[2];
            #pragma unroll
            for (int nt = 0; nt < 2; ++nt) {
                f32x4 acc = {0.0f, 0.0f, 0.0f, 0.0f};
                acc = __builtin_amdgcn_mfma_f32_16x16x32_bf16(kf0, qf[nt][0], acc, 0, 0, 0);
                acc = __builtin_amdgcn_mfma_f32_16x16x32_bf16(kf1, qf[nt][1], acc, 0, 0, 0);
                sacc[nt] = acc;
            }

            // causal mask on the diagonal tile
            if (t == nkt - 1) {
                const int kgb = t * 64 + ks * 16 + quad * 4;
                #pragma unroll
                for (int nt = 0; nt < 2; ++nt) {
                    const int qg = qb + qh * 32 + nt * 16 + m16;
                    #pragma unroll
                    for (int r = 0; r < 4; ++r)
                        if (kgb + r > qg) sacc[nt][r] = -1.0e30f;
                }
            }

            // fixed-base softmax + pack P^T straight into the MFMA16 B operand
            bf16x4 pb[2];
            #pragma unroll
            for (int nt = 0; nt < 2; ++nt) {
                #pragma unroll
                for (int r = 0; r < 4; ++r) {
                    const float e = __builtin_amdgcn_exp2f(sacc[nt][r]);
                    sacc[nt][r] = e;
                    l_l[nt] += e;
                    e_m[nt] = fmaxf(e_m[nt], e);
                }
                union { unsigned int u[2]; bf16x4 h; } cv;
                cv.u[0] = pkbf(sacc[nt][0], sacc[nt][1]);
                cv.u[1] = pkbf(sacc[nt][2], sacc[nt][3]);
                pb[nt] = cv.h;
            }

            // O^T += V^T(k-slice) P^T (identity layout, no LDS roundtrip)
            #pragma unroll
            for (int dt = 0; dt < 4; ++dt) {
                bf16x4 vf = *(const bf16x4*)&Vt[(dt * 16 + m16) * 64 + vsw];
                #pragma unroll
                for (int nt = 0; nt < 2; ++nt)
                    Oacc[dt][nt] = MFMA16(vf, pb[nt], Oacc[dt][nt]);
            }

            if (pf) {  // commit prefetch (tid-linear, conflict-free)
                *(u16x8*)&Ksh[b ^ 1][lds0] = kpf0;
                *(u16x8*)&Ksh[b ^ 1][lds1] = kpf1;
                *(u16x8*)&Vsh[b ^ 1][lds0] = vpf0;
                *(u16x8*)&Vsh[b ^ 1][lds1] = vpf1;
            }
            __syncthreads();
        }

        // ---- per-pass reductions ----
        #pragma unroll
        for (int nt = 0; nt < 2; ++nt) {
            l_l[nt] += __shfl_xor(l_l[nt], 16);
            l_l[nt] += __shfl_xor(l_l[nt], 32);
            e_m[nt] = fmaxf(e_m[nt], __shfl_xor(e_m[nt], 16));
            e_m[nt] = fmaxf(e_m[nt], __shfl_xor(e_m[nt], 32));
        }
        if (quad == 0) {
            #pragma unroll
            for (int nt = 0; nt < 2; ++nt) {
                Lred[ks][nt][m16] = l_l[nt];
                Ered[ks][nt][m16] = e_m[nt];
            }
        }

        // O tree-reduction over 4 k-slices via 16KB overlay (2 slots x 8KB)
        const int lsw = lane * 32;
        if (ks >= 2) {
            const int s = (ks - 2) * 2048;
            #pragma unroll
            for (int i = 0; i < 8; ++i)
                *(f32x4*)&Ored[s + lsw + ((i ^ (lane & 7)) << 2)] = Oacc[i >> 1][i & 1];
        }
        __syncthreads();
        if (ks < 2) {
            const int s = ks * 2048;
            #pragma unroll
            for (int i = 0; i < 8; ++i) {
                f32x4 a = *(const f32x4*)&Ored[s + lsw + ((i ^ (lane & 7)) << 2)];
                #pragma unroll
                for (int r = 0; r < 4; ++r) Oacc[i >> 1][i & 1][r] += a[r];
            }
        }
        if (ks == 1) {
            #pragma unroll
            for (int i = 0; i < 8; ++i)
                *(f32x4*)&Ored[2048 + lsw + ((i ^ (lane & 7)) << 2)] = Oacc[i >> 1][i & 1];
        }
        __syncthreads();
        if (ks == 0) {
            #pragma unroll
            for (int i = 0; i < 8; ++i) {
                f32x4 a = *(const f32x4*)&Ored[2048 + lsw + ((i ^ (lane & 7)) << 2)];
                #pragma unroll
                for (int r = 0; r < 4; ++r) Oacc[i >> 1][i & 1][r] += a[r];
            }
            #pragma unroll
            for (int nt = 0; nt < 2; ++nt) {
                float lq = Lred[0][nt][m16] + Lred[1][nt][m16]
                         + Lred[2][nt][m16] + Lred[3][nt][m16];
                float eq = fmaxf(fmaxf(Ered[0][nt][m16], Ered[1][nt][m16]),
                                 fmaxf(Ered[2][nt][m16], Ered[3][nt][m16]));
                amax_s = fmaxf(amax_s, eq / lq);
                const float ivl = ss_ / lq;
                float* oprow = out + base + (size_t)(qb + qh * 32 + nt * 16 + m16) * DD + quad * 4;
                #pragma unroll
                for (int dt = 0; dt < 4; ++dt) {
                    f32x4 ov;
                    #pragma unroll
                    for (int r = 0; r < 4; ++r) {
                        const float o_raw = Oacc[dt][nt][r] * ivl;
                        amax_o = fmaxf(amax_o, fabsf(o_raw));
                        ov[r] = o_raw * o_q;
                    }
                    *(f32x4*)(oprow + dt * 16) = ov;
                }
            }
        }
        __syncthreads();   // LDS reusable for next pass
    }

    if (ks == 0) {
        #pragma unroll
        for (int m = 1; m < 64; m <<= 1) {
            amax_o = fmaxf(amax_o, __shfl_xor(amax_o, m));
            amax_s = fmaxf(amax_s, __shfl_xor(amax_s, m));
        }
        if (lane == 0) {
            atomicMaxPosF(out + OSIZE,     amax_s);
            atomicMaxPosF(out + OSIZE + 1, amax_o);
        }
    }
}

extern "C" void kernel_launch(void* const* d_in, const int* in_sizes, int n_in,
                              void* d_out, int out_size, void* d_ws, size_t ws_size,
                              hipStream_t stream) {
    const float* q   = (const float*)d_in[0];
    const float* k   = (const float*)d_in[1];
    const float* v   = (const float*)d_in[2];
    const float* dsq = (const float*)d_in[3];
    const float* dsk = (const float*)d_in[4];
    const float* dsv = (const float*)d_in[5];
    const float* qss = (const float*)d_in[6];
    const float* qso = (const float*)d_in[7];
    const float* dss = (const float*)d_in[8];
    float* out = (float*)d_out;

    unsigned short* kbf = (unsigned short*)d_ws;            // 8 MB
    unsigned short* vtb = (unsigned short*)d_ws + OSIZE;    // 8 MB

    prep_kv_kernel<<<dim3(SS / 64, BB * HH), 256, 0, stream>>>(k, v, dsk, dsv, kbf, vtb, out);

    // grid: x = bh so flat%8 == bh%8 -> all blocks of a head on one XCD
    // y = x*2 + qh: 1024 blocks of 256 threads -> 4 blocks/CU
    dim3 grid(BB * HH, 32);
    fattn_kernel<<<grid, 256, 0, stream>>>(q, kbf, vtb, dsq, qss, qso, dss, out);
}

// Round 14
// 166.857 us; speedup vs baseline: 1.0491x; 1.0491x over previous
//
#include <hip/hip_runtime.h>

#define BB 2
#define HH 16
#define SS 2048
#define DD 64

constexpr int OSIZE = BB * HH * SS * DD;  // 4,194,304
constexpr float LOG2E = 1.4426950408889634f;

using bf16x8 = __attribute__((ext_vector_type(8))) short;
using bf16x4 = __attribute__((ext_vector_type(4))) short;
using f32x4  = __attribute__((ext_vector_type(4))) float;
using u16x8  = __attribute__((ext_vector_type(8))) unsigned short;
using fl4    = __attribute__((ext_vector_type(4))) float;

// gfx950 K=16 bf16 MFMA (v_mfma_f32_16x16x16_bf16)
#define MFMA16(a, b, c) __builtin_amdgcn_mfma_f32_16x16x16bf16_1k(a, b, c, 0, 0, 0)

__device__ __forceinline__ unsigned short f2bf(float f) {
    unsigned int u = __float_as_uint(f);
    return (unsigned short)((u + 0x7fffu + ((u >> 16) & 1u)) >> 16);
}

// pack two fp32 -> (bf16_hi<<16)|bf16_lo via one v_perm_b32 (truncation)
__device__ __forceinline__ unsigned int pkbf(float lo, float hi) {
    return __builtin_amdgcn_perm(__float_as_uint(hi), __float_as_uint(lo), 0x07060302u);
}

__device__ __forceinline__ void atomicMaxPosF(float* addr, float v) {
    atomicMax(reinterpret_cast<unsigned int*>(addr), __float_as_uint(v));
}

// ---- fused prepass: amax init + K->bf16 convert + V->bf16 transpose ----
__global__ __launch_bounds__(256) void prep_kv_kernel(
    const float* __restrict__ k, const float* __restrict__ v,
    const float* __restrict__ dsk, const float* __restrict__ dsv,
    unsigned short* __restrict__ kbf, unsigned short* __restrict__ vtb,
    float* __restrict__ out)
{
    const int t  = threadIdx.x;
    const int s0 = blockIdx.x * 64;
    const int bh = blockIdx.y;
    if (blockIdx.x == 0 && bh == 0 && t < 2) out[OSIZE + t] = 0.0f;

    const size_t base = (size_t)bh * SS * DD;
    const float sck = dsk[0], scv = dsv[0];

    {
        const float* kp = k + base + (size_t)s0 * DD + t * 16;
        unsigned short* ko = kbf + base + (size_t)s0 * DD + t * 16;
        fl4 a0 = ((const fl4*)kp)[0], a1 = ((const fl4*)kp)[1];
        fl4 a2 = ((const fl4*)kp)[2], a3 = ((const fl4*)kp)[3];
        u16x8 o0, o1;
        #pragma unroll
        for (int j = 0; j < 4; ++j) {
            o0[j] = f2bf(a0[j] * sck); o0[j + 4] = f2bf(a1[j] * sck);
            o1[j] = f2bf(a2[j] * sck); o1[j + 4] = f2bf(a3[j] * sck);
        }
        ((u16x8*)ko)[0] = o0; ((u16x8*)ko)[1] = o1;
    }

    __shared__ unsigned short T[64 * 72];
    {
        const int r  = t >> 2;
        const int cb = (t & 3) * 16;
        const fl4* vp = (const fl4*)(v + base + (size_t)(s0 + r) * DD + cb);
        unsigned short tmp[16];
        #pragma unroll
        for (int c = 0; c < 4; ++c) {
            fl4 xx = vp[c];
            #pragma unroll
            for (int j = 0; j < 4; ++j) tmp[c * 4 + j] = f2bf(xx[j] * scv);
        }
        *(u16x8*)&T[r * 72 + cb]     = *(u16x8*)&tmp[0];
        *(u16x8*)&T[r * 72 + cb + 8] = *(u16x8*)&tmp[8];
    }
    __syncthreads();
    {
        const int dr = t >> 2;
        const int sb = (t & 3) * 16;
        unsigned short tmp[16];
        #pragma unroll
        for (int j = 0; j < 16; ++j) tmp[j] = T[(sb + j) * 72 + dr];
        unsigned short* op = vtb + base + (size_t)dr * SS + s0 + sb;
        *(u16x8*)op       = *(u16x8*)&tmp[0];
        *(u16x8*)(op + 8) = *(u16x8*)&tmp[8];
    }
}

// ---- main kernel: R10 geometry + quad-buffer LDS, 2 tiles per barrier ----
__global__ __launch_bounds__(512, 4) void fattn_kernel(
    const float* __restrict__ q,
    const unsigned short* __restrict__ kbf,     // bf16 K  [bh][s][d], dsk folded
    const unsigned short* __restrict__ vtb,     // bf16 V^T [bh][d][s], dsv folded
    const float* __restrict__ dsq, const float* __restrict__ qss,
    const float* __restrict__ qso, const float* __restrict__ dss,
    float* __restrict__ out)
{
    const int bh = blockIdx.x;                  // flat%8 == bh%8 -> XCD-local K/V
    const int x  = blockIdx.y;                  // 0..15 (qt pair {x, 31-x})
    const int tid  = threadIdx.x;
    const int wave = tid >> 6;
    const int qh   = wave >> 2;                 // q-half: q rows qh*32..+32
    const int ks   = wave & 3;                  // k-slice: 16 k-rows each
    const int lane = tid & 63;
    const int m16  = lane & 15;
    const int quad = lane >> 4;
    const int m7   = m16 & 7;

    // LDS: K quad-buf 32KB + V quad-buf 32KB + reductions 1KB -> 2 blocks/CU
    __shared__ __align__(16) unsigned short Ksh[4][64 * 64];
    __shared__ __align__(16) unsigned short Vsh[4][64 * 64];
    __shared__ float Lred[2][4][2][16];   // [qh][ks][nt][m16]
    __shared__ float Ered[2][4][2][16];

    const float q_scale = dsq[0] * 0.125f * LOG2E;
    const size_t base = (size_t)bh * SS * DD;
    const unsigned short* kbh = kbf + base;
    const unsigned short* vbh = vtb + base;

    // staging: one 16B granule of K and V per thread (512 granules = full tile),
    // tid-linear LDS write, XOR-swizzled source column
    const int srow = tid >> 3;
    const int sgc  = ((tid & 7) ^ (srow & 7)) * 8;
    const int koff = srow * DD + sgc;
    const int voff = srow * SS + sgc;
    const int ldso = tid * 8;

    // fragment read offsets (swizzled granules)
    const int gsw0 = (quad ^ m7) * 8;
    const int gsw1 = ((4 | quad) ^ m7) * 8;
    const int krow = (ks * 16 + m16) * 64;
    const int vg   = ks * 2 + (quad >> 1);
    const int vsw  = ((vg ^ m7) * 8) + (quad & 1) * 4;

    const float ss_ = qss[0] * dss[0];
    const float o_q = qso[0];
    float amax_o = 0.0f, amax_s = 0.0f;

    float* Ored = (float*)&Ksh[0][0];   // 32 KB overlay, 4 slices x 8 KB

    for (int pass = 0; pass < 2; ++pass) {
        const int qt = pass ? (31 - x) : x;
        const int qb = qt * 64;
        const int nkt = qt + 1;

        // Q fragments (B operand) for this wave's 2 q-tiles, prescaled
        bf16x8 qf[2][2];
        #pragma unroll
        for (int nt = 0; nt < 2; ++nt) {
            const float* qp = q + base + (size_t)(qb + qh * 32 + nt * 16 + m16) * DD + quad * 8;
            #pragma unroll
            for (int f = 0; f < 2; ++f) {
                fl4 a = *(const fl4*)(qp + f * 32);
                fl4 b2 = *(const fl4*)(qp + f * 32 + 4);
                #pragma unroll
                for (int j = 0; j < 4; ++j) {
                    qf[nt][f][j]     = (short)f2bf(a[j] * q_scale);
                    qf[nt][f][j + 4] = (short)f2bf(b2[j] * q_scale);
                }
            }
        }

        f32x4 Oacc[4][2];   // O^T partial: row d=dt*16+quad*4+r, col q=nt*16+m16 (+qh*32)
        #pragma unroll
        for (int dt = 0; dt < 4; ++dt)
            #pragma unroll
            for (int nt = 0; nt < 2; ++nt)
                #pragma unroll
                for (int r = 0; r < 4; ++r) Oacc[dt][nt][r] = 0.0f;
        float l_l[2] = {0.0f, 0.0f}, e_m[2] = {0.0f, 0.0f};

        // one tile's compute (reads LDS buf, accumulates softmax + O)
        auto do_tile = [&](int t, int buf) {
            const unsigned short* Kt = &Ksh[buf][0];
            const unsigned short* Vt = &Vsh[buf][0];
            bf16x8 kf0 = *(const bf16x8*)&Kt[krow + gsw0];
            bf16x8 kf1 = *(const bf16x8*)&Kt[krow + gsw1];
            f32x4 sacc[2];
            #pragma unroll
            for (int nt = 0; nt < 2; ++nt) {
                f32x4 acc = {0.0f, 0.0f, 0.0f, 0.0f};
                acc = __builtin_amdgcn_mfma_f32_16x16x32_bf16(kf0, qf[nt][0], acc, 0, 0, 0);
                acc = __builtin_amdgcn_mfma_f32_16x16x32_bf16(kf1, qf[nt][1], acc, 0, 0, 0);
                sacc[nt] = acc;
            }
            if (t == nkt - 1) {   // causal mask on the diagonal tile
                const int kgb = t * 64 + ks * 16 + quad * 4;
                #pragma unroll
                for (int nt = 0; nt < 2; ++nt) {
                    const int qg = qb + qh * 32 + nt * 16 + m16;
                    #pragma unroll
                    for (int r = 0; r < 4; ++r)
                        if (kgb + r > qg) sacc[nt][r] = -1.0e30f;
                }
            }
            // fixed-base softmax + pack P^T straight into the MFMA16 B operand
            bf16x4 pb[2];
            #pragma unroll
            for (int nt = 0; nt < 2; ++nt) {
                #pragma unroll
                for (int r = 0; r < 4; ++r) {
                    const float e = __builtin_amdgcn_exp2f(sacc[nt][r]);
                    sacc[nt][r] = e;
                    l_l[nt] += e;
                    e_m[nt] = fmaxf(e_m[nt], e);
                }
                union { unsigned int u[2]; bf16x4 h; } cv;
                cv.u[0] = pkbf(sacc[nt][0], sacc[nt][1]);
                cv.u[1] = pkbf(sacc[nt][2], sacc[nt][3]);
                pb[nt] = cv.h;
            }
            // O^T += V^T(k-slice) P^T (identity layout, no LDS roundtrip)
            #pragma unroll
            for (int dt = 0; dt < 4; ++dt) {
                bf16x4 vf = *(const bf16x4*)&Vt[(dt * 16 + m16) * 64 + vsw];
                #pragma unroll
                for (int nt = 0; nt < 2; ++nt)
                    Oacc[dt][nt] = MFMA16(vf, pb[nt], Oacc[dt][nt]);
            }
        };

        // prologue: stage tiles 0 (and 1) into buffers 0 (and 1)
        {
            *(u16x8*)&Ksh[0][ldso] = *(const u16x8*)(kbh + koff);
            *(u16x8*)&Vsh[0][ldso] = *(const u16x8*)(vbh + voff);
            if (1 < nkt) {
                *(u16x8*)&Ksh[1][ldso] = *(const u16x8*)(kbh + 64 * DD + koff);
                *(u16x8*)&Vsh[1][ldso] = *(const u16x8*)(vbh + 64 + voff);
            }
        }
        __syncthreads();

        const int n2 = (nkt + 1) >> 1;
        for (int j = 0; j < n2; ++j) {
            const int t0 = 2 * j, t1 = 2 * j + 1;
            const bool pfa = (t0 + 2 < nkt), pfb = (t1 + 2 < nkt);

            // prefetch tiles t0+2, t1+2 (in flight across this whole period)
            u16x8 ka, va, kb2, vb2;
            if (pfa) {
                ka = *(const u16x8*)(kbh + (size_t)(t0 + 2) * 64 * DD + koff);
                va = *(const u16x8*)(vbh + (t0 + 2) * 64 + voff);
            }
            if (pfb) {
                kb2 = *(const u16x8*)(kbh + (size_t)(t1 + 2) * 64 * DD + koff);
                vb2 = *(const u16x8*)(vbh + (t1 + 2) * 64 + voff);
            }

            do_tile(t0, t0 & 3);
            if (t1 < nkt) do_tile(t1, t1 & 3);

            if (pfa) {
                *(u16x8*)&Ksh[(t0 + 2) & 3][ldso] = ka;
                *(u16x8*)&Vsh[(t0 + 2) & 3][ldso] = va;
            }
            if (pfb) {
                *(u16x8*)&Ksh[(t1 + 2) & 3][ldso] = kb2;
                *(u16x8*)&Vsh[(t1 + 2) & 3][ldso] = vb2;
            }
            __syncthreads();
        }

        // ---- per-pass reductions ----
        #pragma unroll
        for (int nt = 0; nt < 2; ++nt) {
            l_l[nt] += __shfl_xor(l_l[nt], 16);
            l_l[nt] += __shfl_xor(l_l[nt], 32);
            e_m[nt] = fmaxf(e_m[nt], __shfl_xor(e_m[nt], 16));
            e_m[nt] = fmaxf(e_m[nt], __shfl_xor(e_m[nt], 32));
        }
        if (quad == 0) {
            #pragma unroll
            for (int nt = 0; nt < 2; ++nt) {
                Lred[qh][ks][nt][m16] = l_l[nt];
                Ered[qh][ks][nt][m16] = e_m[nt];
            }
        }

        // O tree-reduction over k-slices via 32KB overlay (4 slots x 8KB)
        const int lsw = lane * 32;
        if (ks >= 2) {
            const int s = (qh * 2 + (ks - 2)) * 2048;
            #pragma unroll
            for (int i = 0; i < 8; ++i)
                *(f32x4*)&Ored[s + lsw + ((i ^ (lane & 7)) << 2)] = Oacc[i >> 1][i & 1];
        }
        __syncthreads();
        if (ks < 2) {
            const int s = (qh * 2 + ks) * 2048;
            #pragma unroll
            for (int i = 0; i < 8; ++i) {
                f32x4 a = *(const f32x4*)&Ored[s + lsw + ((i ^ (lane & 7)) << 2)];
                #pragma unroll
                for (int r = 0; r < 4; ++r) Oacc[i >> 1][i & 1][r] += a[r];
            }
        }
        if (ks == 1) {
            const int s = (qh * 2 + 1) * 2048;
            #pragma unroll
            for (int i = 0; i < 8; ++i)
                *(f32x4*)&Ored[s + lsw + ((i ^ (lane & 7)) << 2)] = Oacc[i >> 1][i & 1];
        }
        __syncthreads();
        if (ks == 0) {
            const int s = (qh * 2 + 1) * 2048;
            #pragma unroll
            for (int i = 0; i < 8; ++i) {
                f32x4 a = *(const f32x4*)&Ored[s + lsw + ((i ^ (lane & 7)) << 2)];
                #pragma unroll
                for (int r = 0; r < 4; ++r) Oacc[i >> 1][i & 1][r] += a[r];
            }
            #pragma unroll
            for (int nt = 0; nt < 2; ++nt) {
                float lq = Lred[qh][0][nt][m16] + Lred[qh][1][nt][m16]
                         + Lred[qh][2][nt][m16] + Lred[qh][3][nt][m16];
                float eq = fmaxf(fmaxf(Ered[qh][0][nt][m16], Ered[qh][1][nt][m16]),
                                 fmaxf(Ered[qh][2][nt][m16], Ered[qh][3][nt][m16]));
                amax_s = fmaxf(amax_s, eq / lq);
                const float ivl = ss_ / lq;
                float* oprow = out + base + (size_t)(qb + qh * 32 + nt * 16 + m16) * DD + quad * 4;
                #pragma unroll
                for (int dt = 0; dt < 4; ++dt) {
                    f32x4 ov;
                    #pragma unroll
                    for (int r = 0; r < 4; ++r) {
                        const float o_raw = Oacc[dt][nt][r] * ivl;
                        amax_o = fmaxf(amax_o, fabsf(o_raw));
                        ov[r] = o_raw * o_q;
                    }
                    *(f32x4*)(oprow + dt * 16) = ov;
                }
            }
        }
        __syncthreads();   // LDS reusable for next pass
    }

    if (ks == 0) {
        #pragma unroll
        for (int m = 1; m < 64; m <<= 1) {
            amax_o = fmaxf(amax_o, __shfl_xor(amax_o, m));
            amax_s = fmaxf(amax_s, __shfl_xor(amax_s, m));
        }
        if (lane == 0) {
            atomicMaxPosF(out + OSIZE,     amax_s);
            atomicMaxPosF(out + OSIZE + 1, amax_o);
        }
    }
}

extern "C" void kernel_launch(void* const* d_in, const int* in_sizes, int n_in,
                              void* d_out, int out_size, void* d_ws, size_t ws_size,
                              hipStream_t stream) {
    const float* q   = (const float*)d_in[0];
    const float* k   = (const float*)d_in[1];
    const float* v   = (const float*)d_in[2];
    const float* dsq = (const float*)d_in[3];
    const float* dsk = (const float*)d_in[4];
    const float* dsv = (const float*)d_in[5];
    const float* qss = (const float*)d_in[6];
    const float* qso = (const float*)d_in[7];
    const float* dss = (const float*)d_in[8];
    float* out = (float*)d_out;

    unsigned short* kbf = (unsigned short*)d_ws;            // 8 MB
    unsigned short* vtb = (unsigned short*)d_ws + OSIZE;    // 8 MB

    prep_kv_kernel<<<dim3(SS / 64, BB * HH), 256, 0, stream>>>(k, v, dsk, dsv, kbf, vtb, out);

    // grid: x = bh so flat%8 == bh%8 -> all blocks of a head on one XCD
    dim3 grid(BB * HH, 16);
    fattn_kernel<<<grid, 512, 0, stream>>>(q, kbf, vtb, dsq, qss, qso, dss, out);
}